// Round 1
// baseline (213.688 us; speedup 1.0000x reference)
//
#include <hip/hip_runtime.h>
#include <math.h>

#define BATCH 4
#define TLEN 512
#define SLEN 512
#define DM 256
#define NH 4
#define DH 64
#define BT (BATCH * TLEN)   // 2048

__device__ __forceinline__ float rcp_fast(float x) { return __builtin_amdgcn_rcpf(x); }

// ---- shared GEMM inner: acc[8] = X[row0..row0+7][:] @ W[tid][:]  (W stored (out,in), so x @ W.T) ----
__device__ __forceinline__ void gemm8(const float* __restrict__ X,
                                      const float* __restrict__ W,
                                      int row0, int tid,
                                      float (*xs)[DM], float* acc) {
  // cooperative stage of 8 rows of X (8*256 floats = 512 float4, 256 threads x 2)
  const float4* src = (const float4*)(X + (size_t)row0 * DM);
  float4* dstv = (float4*)(&xs[0][0]);
  dstv[tid] = src[tid];
  dstv[tid + 256] = src[tid + 256];
  __syncthreads();
#pragma unroll
  for (int r = 0; r < 8; ++r) acc[r] = 0.f;
  const float4* wr = (const float4*)(W + (size_t)tid * DM);
#pragma unroll 8
  for (int k4 = 0; k4 < DM / 4; ++k4) {
    float4 wv = wr[k4];
#pragma unroll
    for (int r = 0; r < 8; ++r) {
      acc[r] = fmaf(wv.x, xs[r][k4 * 4 + 0], acc[r]);
      acc[r] = fmaf(wv.y, xs[r][k4 * 4 + 1], acc[r]);
      acc[r] = fmaf(wv.z, xs[r][k4 * 4 + 2], acc[r]);
      acc[r] = fmaf(wv.w, xs[r][k4 * 4 + 3], acc[r]);
    }
  }
}

// ---- kernel A: Q/K/V projections, epilogue writes EQ=exp(2Q), EK=exp(2K), V in [bh][t][d] layout ----
__global__ __launch_bounds__(256) void proj_kernel(
    const float* __restrict__ q, const float* __restrict__ k, const float* __restrict__ v,
    const float* __restrict__ wq, const float* __restrict__ wk, const float* __restrict__ wv,
    float* __restrict__ EQ, float* __restrict__ EK, float* __restrict__ Vw) {
  __shared__ float xs[8][DM];
  int tid = threadIdx.x;
  int which = blockIdx.y;
  const float* X = (which == 0) ? q : (which == 1) ? k : v;
  const float* W = (which == 0) ? wq : (which == 1) ? wk : wv;
  float* D = (which == 0) ? EQ : (which == 1) ? EK : Vw;
  int row0 = blockIdx.x * 8;
  float acc[8];
  gemm8(X, W, row0, tid, xs, acc);
  int h = tid >> 6, d = tid & 63;
#pragma unroll
  for (int r = 0; r < 8; ++r) {
    int row = row0 + r;
    int b = row >> 9, t = row & 511;
    float val = acc[r];
    if (which < 2) {
      val = fminf(fmaxf(val, -30.f), 30.f);
      val = __expf(2.0f * val);       // e^{2q}; tanh(q+k) = 1 - 2/(e^{2q}e^{2k}+1)
    }
    D[(((size_t)(b * NH + h) * TLEN) + t) * DH + d] = val;
  }
}

// ---- kernel B: per-wave (b,h,t): scores -> softmax -> attn out -> PV ----
__global__ __launch_bounds__(256) void attn_kernel(
    const float* __restrict__ EQ, const float* __restrict__ EK,
    const float* __restrict__ Vw, const float* __restrict__ va_g,
    float* __restrict__ attn_out, float* __restrict__ attended) {
  __shared__ float s_attn[4][SLEN];
  int tid = threadIdx.x;
  int lane = tid & 63, wid = tid >> 6;
  int bht = blockIdx.x * 4 + wid;            // (b*NH+h)*TLEN + t
  int bh = bht >> 9, t = bht & 511;
  int h = bh & 3, b = bh >> 2;

  // eq row and va row into registers (wave-uniform broadcast loads, fully static indexing)
  float eq[DH], va[DH];
  {
    const float4* eqr = (const float4*)(EQ + (size_t)bht * DH);
    const float4* var_ = (const float4*)(va_g + h * DH);
#pragma unroll
    for (int j = 0; j < DH / 4; ++j) {
      float4 a = eqr[j];
      eq[4 * j + 0] = a.x; eq[4 * j + 1] = a.y; eq[4 * j + 2] = a.z; eq[4 * j + 3] = a.w;
      float4 c = var_[j];
      va[4 * j + 0] = c.x; va[4 * j + 1] = c.y; va[4 * j + 2] = c.z; va[4 * j + 3] = c.w;
    }
  }
  float va_sum = 0.f;
#pragma unroll
  for (int j = 0; j < DH; ++j) va_sum += va[j];

  const float* ekb = EK + (size_t)bh * SLEN * DH;
  float sc[8];
#pragma unroll 1
  for (int i = 0; i < 8; ++i) {
    const float4* ekr = (const float4*)(ekb + (size_t)(i * 64 + lane) * DH);
    float a0 = 0.f, a1 = 0.f, a2 = 0.f, a3 = 0.f;
#pragma unroll
    for (int d4 = 0; d4 < DH / 4; ++d4) {
      float4 e = ekr[d4];
      float p0 = fmaf(eq[4 * d4 + 0], e.x, 1.0f);
      float p1 = fmaf(eq[4 * d4 + 1], e.y, 1.0f);
      float p2 = fmaf(eq[4 * d4 + 2], e.z, 1.0f);
      float p3 = fmaf(eq[4 * d4 + 3], e.w, 1.0f);
      a0 = fmaf(va[4 * d4 + 0], rcp_fast(p0), a0);
      a1 = fmaf(va[4 * d4 + 1], rcp_fast(p1), a1);
      a2 = fmaf(va[4 * d4 + 2], rcp_fast(p2), a2);
      a3 = fmaf(va[4 * d4 + 3], rcp_fast(p3), a3);
    }
    // sum_d va*tanh = va_sum - 2*sum_d va/(p+1);  SCALE = 1/sqrt(64) = 0.125
    sc[i] = (va_sum - 2.0f * ((a0 + a1) + (a2 + a3))) * 0.125f;
  }

  // wave-wide softmax over 512 values (8 per lane)
  float m = sc[0];
#pragma unroll
  for (int i = 1; i < 8; ++i) m = fmaxf(m, sc[i]);
#pragma unroll
  for (int off = 32; off > 0; off >>= 1) m = fmaxf(m, __shfl_xor(m, off));
  float esum = 0.f;
#pragma unroll
  for (int i = 0; i < 8; ++i) { sc[i] = __expf(sc[i] - m); esum += sc[i]; }
#pragma unroll
  for (int off = 32; off > 0; off >>= 1) esum += __shfl_xor(esum, off);
  float inv = rcp_fast(esum);

  float* arow = attn_out + (size_t)bht * SLEN;
#pragma unroll
  for (int i = 0; i < 8; ++i) {
    float a = sc[i] * inv;
    arow[i * 64 + lane] = a;        // coalesced: lanes contiguous
    s_attn[wid][i * 64 + lane] = a;
  }
  __syncthreads();

  // PV: lane = d, loop s; V reads coalesced 256B/instr, attn via LDS broadcast
  const float* vb = Vw + (size_t)bh * SLEN * DH + lane;
  float p0 = 0.f, p1 = 0.f, p2 = 0.f, p3 = 0.f;
#pragma unroll 4
  for (int s = 0; s < SLEN; s += 4) {
    p0 = fmaf(s_attn[wid][s + 0], vb[(s + 0) * DH], p0);
    p1 = fmaf(s_attn[wid][s + 1], vb[(s + 1) * DH], p1);
    p2 = fmaf(s_attn[wid][s + 2], vb[(s + 2) * DH], p2);
    p3 = fmaf(s_attn[wid][s + 3], vb[(s + 3) * DH], p3);
  }
  attended[((size_t)(b * TLEN + t)) * DM + h * DH + lane] = (p0 + p1) + (p2 + p3);
}

// ---- kernel C: out = attended @ w_o.T ----
__global__ __launch_bounds__(256) void outproj_kernel(
    const float* __restrict__ att, const float* __restrict__ wo,
    float* __restrict__ out) {
  __shared__ float xs[8][DM];
  int tid = threadIdx.x;
  int row0 = blockIdx.x * 8;
  float acc[8];
  gemm8(att, wo, row0, tid, xs, acc);
#pragma unroll
  for (int r = 0; r < 8; ++r) out[(size_t)(row0 + r) * DM + tid] = acc[r];
}

extern "C" void kernel_launch(void* const* d_in, const int* in_sizes, int n_in,
                              void* d_out, int out_size, void* d_ws, size_t ws_size,
                              hipStream_t stream) {
  const float* query = (const float*)d_in[0];
  const float* key   = (const float*)d_in[1];
  const float* value = (const float*)d_in[2];
  const float* wq    = (const float*)d_in[3];
  const float* wk    = (const float*)d_in[4];
  const float* wv    = (const float*)d_in[5];
  const float* va    = (const float*)d_in[6];
  const float* wo    = (const float*)d_in[7];

  float* out  = (float*)d_out;                 // (B,T,DM) = 524288 floats
  float* attn = out + (size_t)BT * DM;         // (B,H,T,S) = 4194304 floats

  float* EQ  = (float*)d_ws;                   // [bh][t][d]  2 MB
  float* EK  = EQ + (size_t)BT * DM;           // [bh][s][d]  2 MB
  float* Vw  = EK + (size_t)BT * DM;           // [bh][s][d]  2 MB
  float* att = Vw + (size_t)BT * DM;           // [b][t][h*64+d]  2 MB

  proj_kernel<<<dim3(BT / 8, 3), 256, 0, stream>>>(query, key, value, wq, wk, wv, EQ, EK, Vw);
  attn_kernel<<<dim3((BATCH * NH * TLEN) / 4), 256, 0, stream>>>(EQ, EK, Vw, va, attn, att);
  outproj_kernel<<<dim3(BT / 8), 256, 0, stream>>>(att, wo, out);
}

// Round 2
// 117.129 us; speedup vs baseline: 1.8244x; 1.8244x over previous
//
#include <hip/hip_runtime.h>
#include <math.h>

#define BATCH 4
#define TLEN 512
#define SLEN 512
#define DM 256
#define NH 4
#define DH 64
#define BT (BATCH * TLEN)   // 2048

__device__ __forceinline__ float rcp_fast(float x) { return __builtin_amdgcn_rcpf(x); }
__device__ __forceinline__ float bcast(float x, int l) {
  return __uint_as_float(__builtin_amdgcn_readlane(__float_as_uint(x), l));
}

// ---- shared GEMM inner: acc[8] = X[row0..row0+7][:] @ W[tid][:]  (W stored (out,in), so x @ W.T) ----
__device__ __forceinline__ void gemm8(const float* __restrict__ X,
                                      const float* __restrict__ W,
                                      int row0, int tid,
                                      float (*xs)[DM], float* acc) {
  const float4* src = (const float4*)(X + (size_t)row0 * DM);
  float4* dstv = (float4*)(&xs[0][0]);
  dstv[tid] = src[tid];
  dstv[tid + 256] = src[tid + 256];
  __syncthreads();
#pragma unroll
  for (int r = 0; r < 8; ++r) acc[r] = 0.f;
  const float4* wr = (const float4*)(W + (size_t)tid * DM);
#pragma unroll 8
  for (int k4 = 0; k4 < DM / 4; ++k4) {
    float4 wv = wr[k4];
#pragma unroll
    for (int r = 0; r < 8; ++r) {
      float4 xv = *(const float4*)&xs[r][k4 * 4];   // b128 broadcast instead of 4x b32
      acc[r] = fmaf(wv.x, xv.x, acc[r]);
      acc[r] = fmaf(wv.y, xv.y, acc[r]);
      acc[r] = fmaf(wv.z, xv.z, acc[r]);
      acc[r] = fmaf(wv.w, xv.w, acc[r]);
    }
  }
}

// ---- kernel A: Q/K/V projections. EQ=[bh][t][d] e^{2q}; EKT=[bh][d][s] e^{2k}; V=[bh][s][d] ----
__global__ __launch_bounds__(256) void proj_kernel(
    const float* __restrict__ q, const float* __restrict__ k, const float* __restrict__ v,
    const float* __restrict__ wq, const float* __restrict__ wk, const float* __restrict__ wv,
    float* __restrict__ EQ, float* __restrict__ EKT, float* __restrict__ Vw) {
  __shared__ float xs[8][DM];
  int tid = threadIdx.x;
  int which = blockIdx.y;
  const float* X = (which == 0) ? q : (which == 1) ? k : v;
  const float* W = (which == 0) ? wq : (which == 1) ? wk : wv;
  int row0 = blockIdx.x * 8;
  float acc[8];
  gemm8(X, W, row0, tid, xs, acc);
  int h = tid >> 6, d = tid & 63;
#pragma unroll
  for (int r = 0; r < 8; ++r) {
    int row = row0 + r;
    int b = row >> 9, t = row & 511;
    int bh = b * NH + h;
    float val = acc[r];
    if (which < 2) {
      val = fminf(fmaxf(val, -30.f), 30.f);
      val = __expf(2.0f * val);       // e^{2q}; tanh(q+k) = 1 - 2/(e^{2q}e^{2k}+1)
    }
    if (which == 1) {
      EKT[((size_t)bh * DH + d) * SLEN + t] = val;           // d-major for LDS staging
    } else {
      float* D = (which == 0) ? EQ : Vw;
      D[((size_t)bh * TLEN + t) * DH + d] = val;
    }
  }
}

// ---- kernel B: block = (bh, 8 t-rows); waves own 2 t each; lane = s ----
__global__ __launch_bounds__(256) void attn_kernel(
    const float* __restrict__ EQ, const float* __restrict__ EKT,
    const float* __restrict__ Vw, const float* __restrict__ va_g,
    float* __restrict__ attn_out, float* __restrict__ attended) {
  __shared__ float ek_lds[8][SLEN];          // 16 KB d-major slice
  int tid = threadIdx.x;
  int lane = tid & 63, wid = tid >> 6;
  int bh = blockIdx.x >> 6;                  // 64 blocks per bh
  int t_blk = (blockIdx.x & 63) * 8;
  int h = bh & 3, b = bh >> 2;
  int t0 = t_blk + wid * 2;                  // this wave's 2 t rows

  float acc[2][8];
#pragma unroll
  for (int t = 0; t < 2; ++t)
#pragma unroll
    for (int i = 0; i < 8; ++i) acc[t][i] = 0.f;
  float vsum = 0.f;

  const float* ektb = EKT + (size_t)bh * DH * SLEN;

#pragma unroll 1
  for (int dc = 0; dc < 8; ++dc) {
    __syncthreads();                         // previous slice fully consumed
    {
      const float4* src = (const float4*)(ektb + (size_t)dc * 8 * SLEN);
      float4* dst = (float4*)&ek_lds[0][0];
#pragma unroll
      for (int i = 0; i < 4; ++i) dst[tid + 256 * i] = src[tid + 256 * i];
    }
    __syncthreads();

    // wave-uniform eq (2t x 8d) and va (8d) from L1/L2
    float eq[2][8], va[8];
#pragma unroll
    for (int t = 0; t < 2; ++t) {
      const float4* ep = (const float4*)(EQ + ((size_t)bh * TLEN + t0 + t) * DH + dc * 8);
      float4 a = ep[0], c = ep[1];
      eq[t][0] = a.x; eq[t][1] = a.y; eq[t][2] = a.z; eq[t][3] = a.w;
      eq[t][4] = c.x; eq[t][5] = c.y; eq[t][6] = c.z; eq[t][7] = c.w;
    }
    {
      const float4* vp = (const float4*)(va_g + h * DH + dc * 8);
      float4 a = vp[0], c = vp[1];
      va[0] = a.x; va[1] = a.y; va[2] = a.z; va[3] = a.w;
      va[4] = c.x; va[5] = c.y; va[6] = c.z; va[7] = c.w;
#pragma unroll
      for (int j = 0; j < 8; ++j) vsum += va[j];
    }

#pragma unroll
    for (int sc = 0; sc < 8; ++sc) {
      int s = sc * 64 + lane;
      float ek[8];
#pragma unroll
      for (int j = 0; j < 8; ++j) ek[j] = ek_lds[j][s];   // bank = s%32: 2-way, free
#pragma unroll
      for (int j = 0; j < 8; ++j) {
        float r0 = rcp_fast(fmaf(eq[0][j], ek[j], 1.0f));
        acc[0][sc] = fmaf(va[j], r0, acc[0][sc]);
        float r1 = rcp_fast(fmaf(eq[1][j], ek[j], 1.0f));
        acc[1][sc] = fmaf(va[j], r1, acc[1][sc]);
      }
    }
  }

  // softmax per t over 512 (8 regs x 64 lanes); overwrite acc with probabilities
  size_t bht0 = (size_t)bh * TLEN + t0;
#pragma unroll
  for (int t = 0; t < 2; ++t) {
    float sc_[8];
    float m = -1e30f;
#pragma unroll
    for (int i = 0; i < 8; ++i) { sc_[i] = (vsum - 2.0f * acc[t][i]) * 0.125f; m = fmaxf(m, sc_[i]); }
#pragma unroll
    for (int off = 32; off; off >>= 1) m = fmaxf(m, __shfl_xor(m, off));
    float es = 0.f;
#pragma unroll
    for (int i = 0; i < 8; ++i) { sc_[i] = __expf(sc_[i] - m); es += sc_[i]; }
#pragma unroll
    for (int off = 32; off; off >>= 1) es += __shfl_xor(es, off);
    float inv = rcp_fast(es);
    float* arow = attn_out + (bht0 + t) * SLEN;
#pragma unroll
    for (int i = 0; i < 8; ++i) {
      acc[t][i] = sc_[i] * inv;
      arow[i * 64 + lane] = acc[t][i];
    }
  }

  // PV: lane = d; probs broadcast from registers via readlane (SGPR operand)
  const float* vb = Vw + (size_t)bh * SLEN * DH + lane;
  float f0 = 0.f, f1 = 0.f;
#pragma unroll 1
  for (int sc = 0; sc < 8; ++sc) {
    float p0 = acc[0][sc], p1 = acc[1][sc];
#pragma unroll 8
    for (int j = 0; j < 64; ++j) {
      float vv = vb[(size_t)(sc * 64 + j) * DH];
      f0 = fmaf(bcast(p0, j), vv, f0);
      f1 = fmaf(bcast(p1, j), vv, f1);
    }
  }
  attended[((size_t)(b * TLEN) + t0) * DM + h * DH + lane] = f0;
  attended[((size_t)(b * TLEN) + t0 + 1) * DM + h * DH + lane] = f1;
}

// ---- kernel C: out = attended @ w_o.T ----
__global__ __launch_bounds__(256) void outproj_kernel(
    const float* __restrict__ att, const float* __restrict__ wo,
    float* __restrict__ out) {
  __shared__ float xs[8][DM];
  int tid = threadIdx.x;
  int row0 = blockIdx.x * 8;
  float acc[8];
  gemm8(att, wo, row0, tid, xs, acc);
#pragma unroll
  for (int r = 0; r < 8; ++r) out[(size_t)(row0 + r) * DM + tid] = acc[r];
}

extern "C" void kernel_launch(void* const* d_in, const int* in_sizes, int n_in,
                              void* d_out, int out_size, void* d_ws, size_t ws_size,
                              hipStream_t stream) {
  const float* query = (const float*)d_in[0];
  const float* key   = (const float*)d_in[1];
  const float* value = (const float*)d_in[2];
  const float* wq    = (const float*)d_in[3];
  const float* wk    = (const float*)d_in[4];
  const float* wv    = (const float*)d_in[5];
  const float* va    = (const float*)d_in[6];
  const float* wo    = (const float*)d_in[7];

  float* out  = (float*)d_out;                 // (B,T,DM) = 524288 floats
  float* attn = out + (size_t)BT * DM;         // (B,H,T,S) = 4194304 floats

  float* EQ  = (float*)d_ws;                   // [bh][t][d]  2 MB
  float* EKT = EQ + (size_t)BT * DM;           // [bh][d][s]  2 MB
  float* Vw  = EKT + (size_t)BT * DM;          // [bh][s][d]  2 MB
  float* att = Vw + (size_t)BT * DM;           // [b][t][h*64+d]  2 MB

  proj_kernel<<<dim3(BT / 8, 3), 256, 0, stream>>>(query, key, value, wq, wk, wv, EQ, EKT, Vw);
  attn_kernel<<<dim3(16 * 64), 256, 0, stream>>>(EQ, EKT, Vw, va, attn, att);
  outproj_kernel<<<dim3(BT / 8), 256, 0, stream>>>(att, wo, out);
}

// Round 3
// 115.414 us; speedup vs baseline: 1.8515x; 1.0149x over previous
//
#include <hip/hip_runtime.h>
#include <math.h>

#define BATCH 4
#define TLEN 512
#define SLEN 512
#define DM 256
#define NH 4
#define DH 64
#define BT (BATCH * TLEN)   // 2048

__device__ __forceinline__ float rcp_fast(float x) { return __builtin_amdgcn_rcpf(x); }

#define GLD_LDS16(g, l) __builtin_amdgcn_global_load_lds( \
    (const __attribute__((address_space(1))) void*)(g),   \
    (__attribute__((address_space(3))) void*)(l), 16, 0, 0)

// ---- 64x64 tile transpose: dst[k][o] = src[o][k], matrices are DMxDM ----
__device__ __forceinline__ void transpose_tile(const float* __restrict__ S,
                                               float* __restrict__ D, int bx) {
  __shared__ float tile[64][65];
  int to = (bx & 3) * 64;     // o tile
  int tk = (bx >> 2) * 64;    // k tile
  int lo = threadIdx.x >> 6;  // 0..3
  int lk = threadIdx.x & 63;
#pragma unroll
  for (int p = 0; p < 16; ++p) {
    int o = p * 4 + lo;
    tile[o][lk] = S[(size_t)(to + o) * DM + tk + lk];
  }
  __syncthreads();
#pragma unroll
  for (int p = 0; p < 16; ++p) {
    int kk = p * 4 + lo;
    D[(size_t)(tk + kk) * DM + to + lk] = tile[lk][kk];
  }
}

__global__ __launch_bounds__(256) void transpose3_kernel(
    const float* __restrict__ a, const float* __restrict__ b, const float* __restrict__ c,
    float* __restrict__ ta, float* __restrict__ tb, float* __restrict__ tc) {
  int m = blockIdx.y;
  transpose_tile(m == 0 ? a : (m == 1 ? b : c),
                 m == 0 ? ta : (m == 1 ? tb : tc), blockIdx.x);
}

__global__ __launch_bounds__(256) void transpose1_kernel(
    const float* __restrict__ a, float* __restrict__ ta) {
  transpose_tile(a, ta, blockIdx.x);
}

// ---- GEMM: acc[r] = X[row0+r][:] . WT[:][tid]; X rows are block-uniform -> scalar loads ----
__device__ __forceinline__ void gemm8s(const float* __restrict__ xb,
                                       const float* __restrict__ wt,
                                       int tid, float* acc) {
#pragma unroll
  for (int r = 0; r < 8; ++r) acc[r] = 0.f;
#pragma unroll 8
  for (int kk = 0; kk < DM; ++kk) {
    float w = wt[(size_t)kk * DM + tid];   // coalesced 256B across lanes
#pragma unroll
    for (int r = 0; r < 8; ++r)
      acc[r] = fmaf(xb[r * DM + kk], w, acc[r]);  // xb uniform -> s_load
  }
}

// ---- kernel A: Q/K/V projections. EQ=[bh][t][d] e^{2q}; EKT=[bh][d][s] e^{2k};
//      Vw = s-paired [bh][s/2][d][2] ----
__global__ __launch_bounds__(256) void proj_kernel(
    const float* __restrict__ q, const float* __restrict__ k, const float* __restrict__ v,
    const float* __restrict__ wqt, const float* __restrict__ wkt, const float* __restrict__ wvt,
    float* __restrict__ EQ, float* __restrict__ EKT, float* __restrict__ Vw) {
  int tid = threadIdx.x;
  int which = blockIdx.y;
  const float* X = (which == 0) ? q : (which == 1) ? k : v;
  const float* WT = (which == 0) ? wqt : (which == 1) ? wkt : wvt;
  int row0 = blockIdx.x * 8;
  float acc[8];
  gemm8s(X + (size_t)row0 * DM, WT, tid, acc);
  int h = tid >> 6, d = tid & 63;
#pragma unroll
  for (int r = 0; r < 8; ++r) {
    int row = row0 + r;
    int b = row >> 9, t = row & 511;
    int bh = b * NH + h;
    float val = acc[r];
    if (which < 2) {
      val = fminf(fmaxf(val, -30.f), 30.f);
      val = __expf(2.0f * val);       // tanh(q+k) = 1 - 2/(e^{2q}e^{2k}+1)
    }
    if (which == 0) {
      EQ[((size_t)bh * TLEN + t) * DH + d] = val;
    } else if (which == 1) {
      EKT[((size_t)bh * DH + d) * SLEN + t] = val;           // d-major for LDS staging
    } else {
      Vw[(size_t)bh * SLEN * DH + (((t >> 1) * DH + d) << 1) + (t & 1)] = val;
    }
  }
}

// ---- kernel B: block = (bh, 8 t-rows); 4 waves x 2 t; lane = s in score, lane = d in PV ----
__global__ __launch_bounds__(256) void attn_kernel(
    const float* __restrict__ EQ, const float* __restrict__ EKT,
    const float* __restrict__ Vw, const float* __restrict__ va_g,
    float* __restrict__ attn_out, float* __restrict__ attended) {
  __shared__ float smem[8192];   // [2][8][512] ek double-buffer; later probs [4][512][2]
  int tid = threadIdx.x;
  int lane = tid & 63, wid = tid >> 6;
  int bh = blockIdx.x >> 6;
  int t_blk = (blockIdx.x & 63) * 8;
  int h = bh & 3, b = bh >> 2;
  int t0 = t_blk + wid * 2;

  const float* ektb = EKT + (size_t)bh * DH * SLEN;

  // stage one 16KB slice (8 d-rows x 512 s) into buf via async direct-to-LDS
#define ISSUE_STAGE(dc_, buf_) do {                                         \
    const float* _s = ektb + (size_t)(dc_) * 4096 + tid * 4;                \
    float* _l = smem + (buf_) * 4096 + wid * 256;                           \
    GLD_LDS16(_s,          _l);                                             \
    GLD_LDS16(_s + 1024,   _l + 1024);                                     \
    GLD_LDS16(_s + 2048,   _l + 2048);                                     \
    GLD_LDS16(_s + 3072,   _l + 3072);                                     \
  } while (0)

  float acc0[8], acc1[8];
#pragma unroll
  for (int i = 0; i < 8; ++i) { acc0[i] = 0.f; acc1[i] = 0.f; }
  float vsum = 0.f;

  ISSUE_STAGE(0, 0);

#pragma unroll 1
  for (int dc = 0; dc < 8; ++dc) {
    int buf = dc & 1;

    // wave-uniform eq (2t x 8d) and va (8d); these loads precede the vmcnt wait below
    float eq0[8], eq1[8], va[8];
    {
      const float4* e0 = (const float4*)(EQ + ((size_t)bh * TLEN + t0) * DH + dc * 8);
      const float4* e1 = (const float4*)(EQ + ((size_t)bh * TLEN + t0 + 1) * DH + dc * 8);
      const float4* vp = (const float4*)(va_g + h * DH + dc * 8);
      float4 a0 = e0[0], b0 = e0[1], a1 = e1[0], b1 = e1[1], av = vp[0], bv = vp[1];
      eq0[0]=a0.x; eq0[1]=a0.y; eq0[2]=a0.z; eq0[3]=a0.w; eq0[4]=b0.x; eq0[5]=b0.y; eq0[6]=b0.z; eq0[7]=b0.w;
      eq1[0]=a1.x; eq1[1]=a1.y; eq1[2]=a1.z; eq1[3]=a1.w; eq1[4]=b1.x; eq1[5]=b1.y; eq1[6]=b1.z; eq1[7]=b1.w;
      va[0]=av.x; va[1]=av.y; va[2]=av.z; va[3]=av.w; va[4]=bv.x; va[5]=bv.y; va[6]=bv.z; va[7]=bv.w;
#pragma unroll
      for (int j = 0; j < 8; ++j) vsum += va[j];
    }

    if (dc < 7) {
      ISSUE_STAGE(dc + 1, buf ^ 1);                 // prefetch next slice
      asm volatile("s_waitcnt vmcnt(4)" ::: "memory");  // current slice (+eq) landed
    } else {
      asm volatile("s_waitcnt vmcnt(0)" ::: "memory");
    }
    __builtin_amdgcn_s_barrier();                   // everyone's current slice ready
    __builtin_amdgcn_sched_barrier(0);

    const float* ek = smem + buf * 4096;
#pragma unroll
    for (int sc = 0; sc < 8; ++sc) {
      int s = sc * 64 + lane;
#pragma unroll
      for (int j = 0; j < 8; ++j) {
        float ekv = ek[j * 512 + s];                // bank = s%32: 2-way, free
        float r0 = rcp_fast(fmaf(eq0[j], ekv, 1.0f));
        acc0[sc] = fmaf(va[j], r0, acc0[sc]);
        float r1 = rcp_fast(fmaf(eq1[j], ekv, 1.0f));
        acc1[sc] = fmaf(va[j], r1, acc1[sc]);
      }
    }
    __builtin_amdgcn_sched_barrier(0);
    asm volatile("" ::: "memory");
    __builtin_amdgcn_s_barrier();                   // all done reading buf before overwrite
  }

  // softmax per t over 512 (8 regs x 64 lanes)
  size_t bht0 = (size_t)bh * TLEN + t0;
  float p0_[8], p1_[8];
#pragma unroll
  for (int t = 0; t < 2; ++t) {
    float* accT = t ? acc1 : acc0;
    float sc_[8];
    float m = -1e30f;
#pragma unroll
    for (int i = 0; i < 8; ++i) { sc_[i] = (vsum - 2.0f * accT[i]) * 0.125f; m = fmaxf(m, sc_[i]); }
#pragma unroll
    for (int off = 32; off; off >>= 1) m = fmaxf(m, __shfl_xor(m, off));
    float es = 0.f;
#pragma unroll
    for (int i = 0; i < 8; ++i) { sc_[i] = __expf(sc_[i] - m); es += sc_[i]; }
#pragma unroll
    for (int off = 32; off; off >>= 1) es += __shfl_xor(es, off);
    float inv = rcp_fast(es);
    float* arow = attn_out + (bht0 + t) * SLEN;
    float* pT = t ? p1_ : p0_;
#pragma unroll
    for (int i = 0; i < 8; ++i) {
      float p = sc_[i] * inv;
      pT[i] = p;
      arow[i * 64 + lane] = p;                      // coalesced
    }
  }

  // pack probs [s][2t] into own wave's LDS region (disjoint from buf1 still in use elsewhere)
  float* pw = smem + wid * 1024;
#pragma unroll
  for (int i = 0; i < 8; ++i) {
    int s = i * 64 + lane;
    *(float2*)&pw[s * 2] = make_float2(p0_[i], p1_[i]);   // b64, stride 8B: conflict-free
  }

  // PV: lane = d; per s-pair: 1 broadcast ds_read_b128 + 1 coalesced b64 V load + 4 fma
  const float* vb2 = Vw + (size_t)bh * SLEN * DH + lane * 2;
  float f0 = 0.f, f1 = 0.f;
#pragma unroll 4
  for (int s2 = 0; s2 < 256; ++s2) {
    float4 pp = *(const float4*)&pw[s2 * 4];
    float2 vv = *(const float2*)&vb2[(size_t)s2 * 128];
    f0 = fmaf(pp.x, vv.x, f0);
    f1 = fmaf(pp.y, vv.x, f1);
    f0 = fmaf(pp.z, vv.y, f0);
    f1 = fmaf(pp.w, vv.y, f1);
  }
  attended[((size_t)(b * TLEN) + t0) * DM + h * DH + lane] = f0;
  attended[((size_t)(b * TLEN) + t0 + 1) * DM + h * DH + lane] = f1;
}

// ---- kernel C: out = attended @ w_o.T (reads ws, writes d_out: out-of-place) ----
__global__ __launch_bounds__(256) void outproj_kernel(
    const float* __restrict__ att, const float* __restrict__ wot,
    float* __restrict__ out) {
  int tid = threadIdx.x;
  int row0 = blockIdx.x * 8;
  float acc[8];
  gemm8s(att + (size_t)row0 * DM, wot, tid, acc);
#pragma unroll
  for (int r = 0; r < 8; ++r) out[(size_t)(row0 + r) * DM + tid] = acc[r];
}

extern "C" void kernel_launch(void* const* d_in, const int* in_sizes, int n_in,
                              void* d_out, int out_size, void* d_ws, size_t ws_size,
                              hipStream_t stream) {
  const float* query = (const float*)d_in[0];
  const float* key   = (const float*)d_in[1];
  const float* value = (const float*)d_in[2];
  const float* wq    = (const float*)d_in[3];
  const float* wk    = (const float*)d_in[4];
  const float* wv    = (const float*)d_in[5];
  const float* va    = (const float*)d_in[6];
  const float* wo    = (const float*)d_in[7];

  float* out  = (float*)d_out;                 // (B,T,DM)
  float* attn = out + (size_t)BT * DM;         // (B,H,T,S)

  float* EQ  = (float*)d_ws;                   // 2MB  [bh][t][d]
  float* EKT = EQ + (size_t)BT * DM;           // 2MB  [bh][d][s]   (WoT overlays after attn)
  float* Vw  = EKT + (size_t)BT * DM;          // 2MB  [bh][s/2][d][2]
  float* att = Vw + (size_t)BT * DM;           // 2MB  [b][t][h*64+d] (WTq/k/v overlay before attn)
  float* WTq = att;                            // 256KB each, dead once proj_kernel finishes
  float* WTk = att + 65536;
  float* WTv = att + 131072;
  float* WoT = EKT;                            // written after attn_kernel, read by outproj

  transpose3_kernel<<<dim3(16, 3), 256, 0, stream>>>(wq, wk, wv, WTq, WTk, WTv);
  proj_kernel<<<dim3(BT / 8, 3), 256, 0, stream>>>(query, key, value, WTq, WTk, WTv, EQ, EKT, Vw);
  attn_kernel<<<dim3(16 * 64), 256, 0, stream>>>(EQ, EKT, Vw, va, attn, att);
  transpose1_kernel<<<dim3(16), 256, 0, stream>>>(wo, WoT);
  outproj_kernel<<<dim3(BT / 8), 256, 0, stream>>>(att, WoT, out);
}

// Round 4
// 113.522 us; speedup vs baseline: 1.8824x; 1.0167x over previous
//
#include <hip/hip_runtime.h>
#include <math.h>

#define BATCH 4
#define TLEN 512
#define SLEN 512
#define DM 256
#define NH 4
#define DH 64
#define BT (BATCH * TLEN)   // 2048

__device__ __forceinline__ float rcp_fast(float x) { return __builtin_amdgcn_rcpf(x); }

#define GLD_LDS16(g, l) __builtin_amdgcn_global_load_lds( \
    (const __attribute__((address_space(1))) void*)(g),   \
    (__attribute__((address_space(3))) void*)(l), 16, 0, 0)

// ---- 64x64 tile transpose: dst[k][o] = src[o][k], matrices are DMxDM ----
__device__ __forceinline__ void transpose_tile(const float* __restrict__ S,
                                               float* __restrict__ D, int bx) {
  __shared__ float tile[64][65];
  int to = (bx & 3) * 64;
  int tk = (bx >> 2) * 64;
  int lo = threadIdx.x >> 6;
  int lk = threadIdx.x & 63;
#pragma unroll
  for (int p = 0; p < 16; ++p) {
    int o = p * 4 + lo;
    tile[o][lk] = S[(size_t)(to + o) * DM + tk + lk];
  }
  __syncthreads();
#pragma unroll
  for (int p = 0; p < 16; ++p) {
    int kk = p * 4 + lo;
    D[(size_t)(tk + kk) * DM + to + lk] = tile[lk][kk];
  }
}

__global__ __launch_bounds__(256) void transpose3_kernel(
    const float* __restrict__ a, const float* __restrict__ b, const float* __restrict__ c,
    float* __restrict__ ta, float* __restrict__ tb, float* __restrict__ tc) {
  int m = blockIdx.y;
  transpose_tile(m == 0 ? a : (m == 1 ? b : c),
                 m == 0 ? ta : (m == 1 ? tb : tc), blockIdx.x);
}

__global__ __launch_bounds__(256) void transpose1_kernel(
    const float* __restrict__ a, float* __restrict__ ta) {
  transpose_tile(a, ta, blockIdx.x);
}

// ---- wave-tiled GEMM: wave computes 4 rows x 256 cols (each lane: 4 rows x float4 cols).
//      X rows wave-uniform -> scalar loads; WT[k][o] -> coalesced float4 (1KB/wave-instr) ----
__device__ __forceinline__ void gemm_wave4(const float* __restrict__ X,
                                           const float* __restrict__ WT,
                                           int o0, float4* acc) {
#pragma unroll
  for (int r = 0; r < 4; ++r) acc[r] = make_float4(0.f, 0.f, 0.f, 0.f);
#pragma unroll 4
  for (int kk = 0; kk < DM; ++kk) {
    float4 w = *(const float4*)(WT + (size_t)kk * DM + o0);
#pragma unroll
    for (int r = 0; r < 4; ++r) {
      float xv = X[r * DM + kk];              // uniform -> s_load
      acc[r].x = fmaf(xv, w.x, acc[r].x);
      acc[r].y = fmaf(xv, w.y, acc[r].y);
      acc[r].z = fmaf(xv, w.z, acc[r].z);
      acc[r].w = fmaf(xv, w.w, acc[r].w);
    }
  }
}

// ---- kernel A: Q/K/V projections. EQ=[bh][t][d]; EKT=[bh][dc16][s][j4]; Vw=[bh][s/2][d][2] ----
__global__ __launch_bounds__(256) void proj_kernel(
    const float* __restrict__ q, const float* __restrict__ k, const float* __restrict__ v,
    const float* __restrict__ wqt, const float* __restrict__ wkt, const float* __restrict__ wvt,
    float* __restrict__ EQ, float* __restrict__ EKT, float* __restrict__ Vw) {
  int tid = threadIdx.x;
  int lane = tid & 63;
  int wid = __builtin_amdgcn_readfirstlane(tid >> 6);
  int which = blockIdx.y;
  const float* X = (which == 0) ? q : (which == 1) ? k : v;
  const float* WT = (which == 0) ? wqt : (which == 1) ? wkt : wvt;
  int row0 = blockIdx.x * 16 + wid * 4;
  int o0 = lane * 4;
  float4 acc[4];
  gemm_wave4(X + (size_t)row0 * DM, WT, o0, acc);
  int h = o0 >> 6, d0 = o0 & 63;
#pragma unroll
  for (int r = 0; r < 4; ++r) {
    int row = row0 + r;
    int b = row >> 9, t = row & 511;
    int bh = b * NH + h;
    float4 a = acc[r];
    if (which < 2) {
      a.x = __expf(2.f * fminf(fmaxf(a.x, -30.f), 30.f));
      a.y = __expf(2.f * fminf(fmaxf(a.y, -30.f), 30.f));
      a.z = __expf(2.f * fminf(fmaxf(a.z, -30.f), 30.f));
      a.w = __expf(2.f * fminf(fmaxf(a.w, -30.f), 30.f));
    }
    if (which == 0) {
      *(float4*)&EQ[((size_t)bh * TLEN + t) * DH + d0] = a;
    } else if (which == 1) {
      *(float4*)&EKT[(((size_t)bh * 16 + (d0 >> 2)) * SLEN + t) * 4] = a;
    } else {
      float* vb = &Vw[(size_t)bh * SLEN * DH + (size_t)(t >> 1) * 128 + d0 * 2 + (t & 1)];
      vb[0] = a.x; vb[2] = a.y; vb[4] = a.z; vb[6] = a.w;
    }
  }
}

// ---- kernel B: 2 waves/block, 2 t-rows/wave; EK slices (4 d x 512 s) double-buffered ----
__global__ __launch_bounds__(128) void attn_kernel(
    const float* __restrict__ EQ, const float* __restrict__ EKT,
    const float* __restrict__ Vw, const float* __restrict__ va_g,
    float* __restrict__ attn_out, float* __restrict__ attended) {
  __shared__ float smem[4096];   // [2][2048] ek dbuf; later probs [2 waves][512][2]
  int tid = threadIdx.x;
  int lane = tid & 63;
  int wid = __builtin_amdgcn_readfirstlane(tid >> 6);
  int bx = (int)((blockIdx.x & 7) * 256 + (blockIdx.x >> 3));  // bijective XCD swizzle (2048 = 8*256)
  int bh = bx >> 7;
  int t0 = (bx & 127) * 4 + wid * 2;
  int h = bh & 3, b = bh >> 2;

  const float* ektb = EKT + (size_t)bh * 16 * SLEN * 4;
  const float* eqp0 = EQ + ((size_t)bh * TLEN + t0) * DH;      // wave-uniform -> scalar loads
  const float* eqp1 = eqp0 + DH;
  const float* vap  = va_g + h * DH;

#define ISSUE_STAGE(dc_, buf_) do {                              \
    const float* _s = ektb + (size_t)(dc_) * 2048 + tid * 4;     \
    float* _l = smem + (buf_) * 2048 + wid * 256;                \
    GLD_LDS16(_s,         _l);                                   \
    GLD_LDS16(_s + 512,   _l + 512);                             \
    GLD_LDS16(_s + 1024,  _l + 1024);                            \
    GLD_LDS16(_s + 1536,  _l + 1536);                            \
  } while (0)

  float acc0[8], acc1[8];
#pragma unroll
  for (int i = 0; i < 8; ++i) { acc0[i] = 0.f; acc1[i] = 0.f; }
  float vsum = 0.f;

  ISSUE_STAGE(0, 0);

#pragma unroll 1
  for (int dc = 0; dc < 16; ++dc) {
    int buf = dc & 1;
    // eq/va: wave-uniform scalar loads (lgkmcnt domain -> no vmcnt interference)
    float4 e0 = *(const float4*)(eqp0 + dc * 4);
    float4 e1 = *(const float4*)(eqp1 + dc * 4);
    float4 av = *(const float4*)(vap + dc * 4);
    vsum += (av.x + av.y) + (av.z + av.w);

    if (dc < 15) {
      ISSUE_STAGE(dc + 1, buf ^ 1);
      asm volatile("s_waitcnt vmcnt(4)" ::: "memory");   // current slice landed; next 4 in flight
    } else {
      asm volatile("s_waitcnt vmcnt(0)" ::: "memory");
    }
    __builtin_amdgcn_s_barrier();
    __builtin_amdgcn_sched_barrier(0);

    const float* ek = smem + buf * 2048;
#pragma unroll
    for (int sc = 0; sc < 8; ++sc) {
      int s = sc * 64 + lane;
      float4 e = *(const float4*)&ek[s * 4];             // one b128, conflict-free
      acc0[sc] = fmaf(av.x, rcp_fast(fmaf(e0.x, e.x, 1.f)), acc0[sc]);
      acc1[sc] = fmaf(av.x, rcp_fast(fmaf(e1.x, e.x, 1.f)), acc1[sc]);
      acc0[sc] = fmaf(av.y, rcp_fast(fmaf(e0.y, e.y, 1.f)), acc0[sc]);
      acc1[sc] = fmaf(av.y, rcp_fast(fmaf(e1.y, e.y, 1.f)), acc1[sc]);
      acc0[sc] = fmaf(av.z, rcp_fast(fmaf(e0.z, e.z, 1.f)), acc0[sc]);
      acc1[sc] = fmaf(av.z, rcp_fast(fmaf(e1.z, e.z, 1.f)), acc1[sc]);
      acc0[sc] = fmaf(av.w, rcp_fast(fmaf(e0.w, e.w, 1.f)), acc0[sc]);
      acc1[sc] = fmaf(av.w, rcp_fast(fmaf(e1.w, e.w, 1.f)), acc1[sc]);
    }
    __builtin_amdgcn_sched_barrier(0);
    asm volatile("" ::: "memory");
    __builtin_amdgcn_s_barrier();                        // all waves done with buf before overwrite
  }

  // softmax per t over 512 (8 regs x 64 lanes)
  size_t bht0 = (size_t)bh * TLEN + t0;
  float p0_[8], p1_[8];
#pragma unroll
  for (int t = 0; t < 2; ++t) {
    float* accT = t ? acc1 : acc0;
    float sc_[8];
    float m = -1e30f;
#pragma unroll
    for (int i = 0; i < 8; ++i) { sc_[i] = (vsum - 2.0f * accT[i]) * 0.125f; m = fmaxf(m, sc_[i]); }
#pragma unroll
    for (int off = 32; off; off >>= 1) m = fmaxf(m, __shfl_xor(m, off));
    float es = 0.f;
#pragma unroll
    for (int i = 0; i < 8; ++i) { sc_[i] = __expf(sc_[i] - m); es += sc_[i]; }
#pragma unroll
    for (int off = 32; off; off >>= 1) es += __shfl_xor(es, off);
    float inv = rcp_fast(es);
    float* arow = attn_out + (bht0 + t) * SLEN;
    float* pT = t ? p1_ : p0_;
#pragma unroll
    for (int i = 0; i < 8; ++i) {
      float p = sc_[i] * inv;
      pT[i] = p;
      arow[i * 64 + lane] = p;                           // coalesced
    }
  }

  // pack probs [s][2t] into own wave's region (dbuf dead; regions disjoint; barrier above)
  float* pw = smem + wid * 1024;
#pragma unroll
  for (int i = 0; i < 8; ++i) {
    int s = i * 64 + lane;
    *(float2*)&pw[s * 2] = make_float2(p0_[i], p1_[i]);
  }

  // PV: lane = d; per s-pair: 1 broadcast b128 + 1 coalesced b64 V load + 4 fma
  const float* vb2 = Vw + (size_t)bh * SLEN * DH + lane * 2;
  float f0 = 0.f, f1 = 0.f;
#pragma unroll 4
  for (int s2 = 0; s2 < 256; ++s2) {
    float4 pp = *(const float4*)&pw[s2 * 4];
    float2 vv = *(const float2*)&vb2[(size_t)s2 * 128];
    f0 = fmaf(pp.x, vv.x, f0);
    f1 = fmaf(pp.y, vv.x, f1);
    f0 = fmaf(pp.z, vv.y, f0);
    f1 = fmaf(pp.w, vv.y, f1);
  }
  attended[((size_t)(b * TLEN) + t0) * DM + h * DH + lane] = f0;
  attended[((size_t)(b * TLEN) + t0 + 1) * DM + h * DH + lane] = f1;
}

// ---- kernel C: out = attended @ w_o.T ----
__global__ __launch_bounds__(256) void outproj_kernel(
    const float* __restrict__ att, const float* __restrict__ wot,
    float* __restrict__ out) {
  int tid = threadIdx.x;
  int lane = tid & 63;
  int wid = __builtin_amdgcn_readfirstlane(tid >> 6);
  int row0 = blockIdx.x * 16 + wid * 4;
  int o0 = lane * 4;
  float4 acc[4];
  gemm_wave4(att + (size_t)row0 * DM, wot, o0, acc);
#pragma unroll
  for (int r = 0; r < 4; ++r)
    *(float4*)&out[(size_t)(row0 + r) * DM + o0] = acc[r];
}

extern "C" void kernel_launch(void* const* d_in, const int* in_sizes, int n_in,
                              void* d_out, int out_size, void* d_ws, size_t ws_size,
                              hipStream_t stream) {
  const float* query = (const float*)d_in[0];
  const float* key   = (const float*)d_in[1];
  const float* value = (const float*)d_in[2];
  const float* wq    = (const float*)d_in[3];
  const float* wk    = (const float*)d_in[4];
  const float* wv    = (const float*)d_in[5];
  const float* va    = (const float*)d_in[6];
  const float* wo    = (const float*)d_in[7];

  float* out  = (float*)d_out;                 // (B,T,DM)
  float* attn = out + (size_t)BT * DM;         // (B,H,T,S)

  float* EQ  = (float*)d_ws;                   // 2MB  [bh][t][d]
  float* EKT = EQ + (size_t)BT * DM;           // 2MB  [bh][dc16][s][j4]  (WoT overlays after attn)
  float* Vw  = EKT + (size_t)BT * DM;          // 2MB  [bh][s/2][d][2]
  float* att = Vw + (size_t)BT * DM;           // 2MB  attended (WTq/k/v overlay before attn)
  float* WTq = att;
  float* WTk = att + 65536;
  float* WTv = att + 131072;
  float* WoT = EKT;

  transpose3_kernel<<<dim3(16, 3), 256, 0, stream>>>(wq, wk, wv, WTq, WTk, WTv);
  proj_kernel<<<dim3(BT / 16, 3), 256, 0, stream>>>(query, key, value, WTq, WTk, WTv, EQ, EKT, Vw);
  attn_kernel<<<dim3(2048), 128, 0, stream>>>(EQ, EKT, Vw, va, attn, att);
  transpose1_kernel<<<dim3(16), 256, 0, stream>>>(wo, WoT);
  outproj_kernel<<<dim3(BT / 16), 256, 0, stream>>>(att, WoT, out);
}